// Round 7
// baseline (280.780 us; speedup 1.0000x reference)
//
#include <hip/hip_runtime.h>
#include <math.h>

// QuantizedAttention: B=2, S=2048, D=1024, H=16, Dh=64.
// Round 6:
//  - flash: paired q-tiles {15-i, i} per block -> 256 blocks x exactly 34 kv-iters (no tail)
//  - flash: P2 stride 72->68 shorts (2-bank/row rotation: 2-way conflicts = free tier)
//  - V GEMM epilogue writes V^T directly (v_trans kernel removed)
//  - amax6 grid 64->256 (was serial/latency-bound)

typedef __attribute__((ext_vector_type(8))) short bf16x8;   // 8 bf16 = 4 VGPRs
typedef __attribute__((ext_vector_type(16))) float f32x16;
typedef __attribute__((ext_vector_type(4))) float f32x4;
typedef __attribute__((ext_vector_type(4))) float f4;

#define E4M3_MAX 448.0f

__device__ inline float bf2f(ushort u) { return __uint_as_float(((unsigned)u) << 16); }
__device__ inline ushort f2bf(float f) {
  unsigned u = __float_as_uint(f);
  return (ushort)((u + 0x7FFF + ((u >> 16) & 1)) >> 16);  // RNE
}
__device__ inline unsigned pack2bf(float a, float b) {  // round-half-up
  unsigned ua = __float_as_uint(a), ub = __float_as_uint(b);
  return ((ua + 0x8000u) >> 16) | ((ub + 0x8000u) & 0xFFFF0000u);
}

// async 16B global -> LDS. Dest must be wave-uniform base + lane*16.
__device__ __forceinline__ void gll16(const ushort* g, ushort* l) {
  __builtin_amdgcn_global_load_lds(
      (const __attribute__((address_space(1))) unsigned int*)g,
      (__attribute__((address_space(3))) unsigned int*)l, 16, 0, 0);
}

__global__ void zero16_kernel(float* p) {
  if (threadIdx.x < 16) p[threadIdx.x] = 0.0f;
}

// 6 tensors in one launch; y selects. Nonneg-float uint atomicMax.
__global__ __launch_bounds__(256) void amax6_kernel(const float* __restrict__ p0,
                                                    const float* __restrict__ p1,
                                                    const float* __restrict__ p2,
                                                    const float* __restrict__ p3,
                                                    const float* __restrict__ p4,
                                                    const float* __restrict__ p5,
                                                    float* __restrict__ amax) {
  int y = blockIdx.y;
  const float* src = (y == 0) ? p0 : (y == 1) ? p1 : (y == 2) ? p2 : (y == 3) ? p3 : (y == 4) ? p4 : p5;
  int n = (y < 3) ? 1048576 : 1024;
  float m = 0.0f;
  int stride = gridDim.x * 256;
  for (int i = blockIdx.x * 256 + threadIdx.x; i < n; i += stride)
    m = fmaxf(m, fabsf(src[i]));
  #pragma unroll
  for (int off = 32; off > 0; off >>= 1)
    m = fmaxf(m, __shfl_xor(m, off));
  __shared__ float wred[4];
  if ((threadIdx.x & 63) == 0) wred[threadIdx.x >> 6] = m;
  __syncthreads();
  if (threadIdx.x == 0) {
    m = fmaxf(fmaxf(wred[0], wred[1]), fmaxf(wred[2], wred[3]));
    atomicMax((unsigned int*)(amax + y), __float_as_uint(m));
  }
}

// e4m3 GRID value (no descale) -- exactly representable in bf16.
__device__ inline float qdq_qval(float w, float amax) {
  float scale = E4M3_MAX / fmaxf(amax, 1e-12f);
  float v = w * scale;
  float a = fmaxf(fabsf(v), 1e-30f);
  int ex;
  (void)frexpf(a, &ex);                 // floor(log2(a)) = ex-1
  float e = fminf(fmaxf((float)(ex - 1), -6.0f), 8.0f);
  float step = exp2f(e - 3.0f);
  float q = rintf(v / step) * step;     // round-half-even matches jnp.round
  return fminf(fmaxf(q, -E4M3_MAX), E4M3_MAX);
}

// 3 bias vectors, one launch (y selects); writes dequantized fp32.
__global__ void qvec3_kernel(const float* __restrict__ b0, const float* __restrict__ b1,
                             const float* __restrict__ b2, const float* __restrict__ amax,
                             float* __restrict__ o0, float* __restrict__ o1,
                             float* __restrict__ o2) {
  int y = blockIdx.y;
  const float* b = (y == 0) ? b0 : (y == 1) ? b1 : b2;
  float* o = (y == 0) ? o0 : (y == 1) ? o1 : o2;
  float am = amax[3 + y];
  int idx = blockIdx.x * blockDim.x + threadIdx.x;
  if (idx < 1024) {
    float q = qdq_qval(b[idx], am);
    o[idx] = q * (fmaxf(am, 1e-12f) * (1.0f / E4M3_MAX));
  }
}

// W [H=16][D=1024][Dh=64] fp32 -> Bt [he=1024][d=1024] bf16 grid values; z selects.
__global__ __launch_bounds__(256) void quant_repack_bt3(const float* __restrict__ W0,
                                                        const float* __restrict__ W1,
                                                        const float* __restrict__ W2,
                                                        const float* __restrict__ amaxp,
                                                        ushort* __restrict__ o0,
                                                        ushort* __restrict__ o1,
                                                        ushort* __restrict__ o2) {
  int z = blockIdx.z;
  const float* W = (z == 0) ? W0 : (z == 1) ? W1 : W2;
  ushort* Bt = (z == 0) ? o0 : (z == 1) ? o1 : o2;
  float amax = amaxp[z];
  __shared__ float tile[64][65];
  int d0 = blockIdx.x * 64, hh = blockIdx.y;
  int tid = threadIdx.x;
  int e = tid & 63, dd = tid >> 6;
  #pragma unroll
  for (int p = 0; p < 16; p++)
    tile[dd + p * 4][e] = W[(size_t)hh * 65536 + (size_t)(d0 + dd + p * 4) * 64 + e];
  __syncthreads();
  int d = tid & 63, ee = tid >> 6;
  #pragma unroll
  for (int p = 0; p < 16; p++) {
    int e2 = ee + p * 4;
    Bt[(size_t)(hh * 64 + e2) * 1024 + d0 + d] = f2bf(qdq_qval(tile[d][e2], amax));
  }
}

// W_O [he=1024][d=1024] fp32 -> woT [d][he] bf16
__global__ __launch_bounds__(256) void wo_trans(const float* __restrict__ W,
                                               ushort* __restrict__ Bt) {
  __shared__ float tile[64][65];
  int d0 = blockIdx.x * 64, he0 = blockIdx.y * 64;
  int tid = threadIdx.x;
  int dcol = tid & 63, hr = tid >> 6;
  #pragma unroll
  for (int p = 0; p < 16; p++)
    tile[hr + p * 4][dcol] = W[(size_t)(he0 + hr + p * 4) * 1024 + d0 + dcol];
  __syncthreads();
  int hcol = tid & 63, dr = tid >> 6;
  #pragma unroll
  for (int p = 0; p < 16; p++)
    Bt[(size_t)(d0 + dr + p * 4) * 1024 + he0 + hcol] = f2bf(tile[hcol][dr + p * 4]);
}

// fp32 -> bf16, 3 tensors in one launch (y selects), 4 elems/thread. grid.x = 4096.
__global__ __launch_bounds__(256) void cvt3_kernel(const float* __restrict__ i0,
                                                   const float* __restrict__ i1,
                                                   const float* __restrict__ i2,
                                                   ushort* __restrict__ o0,
                                                   ushort* __restrict__ o1,
                                                   ushort* __restrict__ o2) {
  int y = blockIdx.y;
  const float* in = (y == 0) ? i0 : (y == 1) ? i1 : i2;
  ushort* out = (y == 0) ? o0 : (y == 1) ? o1 : o2;
  int i = blockIdx.x * 256 + threadIdx.x;
  f4 v = *(const f4*)(in + (size_t)i * 4);
  uint2 o;
  o.x = (unsigned)f2bf(v[0]) | ((unsigned)f2bf(v[1]) << 16);
  o.y = (unsigned)f2bf(v[2]) | ((unsigned)f2bf(v[3]) << 16);
  *(uint2*)(out + (size_t)i * 4) = o;
}

// GEMM body: C = A[M=4096][K=1024] x Bt[N][K]^T, tile 128 x TN, BK=32, 256 thr.
// MODE 0: fp32 out +bias.  MODE 1: bf16 out *s_inv+bias (row-major [row][col]).
// MODE 2: bf16 out *s_inv+bias written TRANSPOSED as vT[(row>>11)*1024+col][row&2047].
template <int MODE, int TN>
__device__ __forceinline__ void gemm_body(const ushort* __restrict__ A,
                                          const ushort* __restrict__ Bt,
                                          const float* __restrict__ bias, float s_inv,
                                          ushort* __restrict__ outb, float* __restrict__ outf,
                                          int bx, int by, ushort* As, ushort* Bs) {
  const int K = 1024, N = 1024;
  const int JF = TN / 32;                 // j-frags per wave
  int tid = threadIdx.x;
  int w = tid >> 6, lane = tid & 63, quad = lane >> 4, l16 = lane & 15;
  int wm = w & 1, wn = w >> 1;
  int row0 = by * 128, col0 = bx * TN;
  f32x4 acc[4][4] = {};

  for (int k0 = 0; k0 < K; k0 += 32) {
    __syncthreads();
    {
      int u = tid;                        // A tile: 128x32 = 512 units of 16B
      gll16(&A[(size_t)(row0 + (u >> 2)) * K + k0 + (u & 3) * 8], &As[u * 8]);
      u = tid + 256;
      gll16(&A[(size_t)(row0 + (u >> 2)) * K + k0 + (u & 3) * 8], &As[u * 8]);
      u = tid;                            // B tile: TN x 32 = TN*4 units
      gll16(&Bt[(size_t)(col0 + (u >> 2)) * K + k0 + (u & 3) * 8], &Bs[u * 8]);
      if (TN == 128) {
        u = tid + 256;
        gll16(&Bt[(size_t)(col0 + (u >> 2)) * K + k0 + (u & 3) * 8], &Bs[u * 8]);
      }
    }
    __syncthreads();                      // compiler drains vmcnt before barrier
    bf16x8 af[4], bfr[JF];
    #pragma unroll
    for (int i = 0; i < 4; i++)
      af[i] = *(const bf16x8*)&As[(wm * 64 + i * 16 + l16) * 32 + quad * 8];
    #pragma unroll
    for (int j = 0; j < JF; j++)
      bfr[j] = *(const bf16x8*)&Bs[(wn * (TN / 2) + j * 16 + l16) * 32 + quad * 8];
    #pragma unroll
    for (int i = 0; i < 4; i++)
      #pragma unroll
      for (int j = 0; j < JF; j++)
        acc[i][j] = __builtin_amdgcn_mfma_f32_16x16x32_bf16(af[i], bfr[j], acc[i][j], 0, 0, 0);
  }

  #pragma unroll
  for (int j = 0; j < JF; j++) {
    int col = col0 + wn * (TN / 2) + j * 16 + l16;
    float bv = bias[col];
    #pragma unroll
    for (int i = 0; i < 4; i++) {
      int row = row0 + wm * 64 + i * 16 + quad * 4;
      if (MODE == 2) {
        float v0 = acc[i][j][0] * s_inv + bv, v1 = acc[i][j][1] * s_inv + bv;
        float v2 = acc[i][j][2] * s_inv + bv, v3 = acc[i][j][3] * s_inv + bv;
        uint2 o;
        o.x = (unsigned)f2bf(v0) | ((unsigned)f2bf(v1) << 16);
        o.y = (unsigned)f2bf(v2) | ((unsigned)f2bf(v3) << 16);
        // rows row..row+3 are 4 consecutive s within one b (tile never crosses b)
        *(uint2*)&outb[((size_t)((row >> 11) * 1024 + col)) * 2048 + (row & 2047)] = o;
      } else {
        #pragma unroll
        for (int r = 0; r < 4; r++) {
          float v = acc[i][j][r] * s_inv + bv;
          if (MODE == 1) outb[(size_t)(row + r) * N + col] = f2bf(v);
          else           outf[(size_t)(row + r) * N + col] = v;
        }
      }
    }
  }
}

// Batched QKV projection: grid (8, 32, 3) = 768 blocks. z=2 writes V^T directly.
__global__ __launch_bounds__(256) void gemm3_qkv(const ushort* __restrict__ xq,
                                                 const ushort* __restrict__ xk,
                                                 const ushort* __restrict__ xv,
                                                 const ushort* __restrict__ wq,
                                                 const ushort* __restrict__ wk,
                                                 const ushort* __restrict__ wv,
                                                 const float* __restrict__ bq,
                                                 const float* __restrict__ bk,
                                                 const float* __restrict__ bv,
                                                 const float* __restrict__ amax,
                                                 ushort* __restrict__ oq,
                                                 ushort* __restrict__ ok,
                                                 ushort* __restrict__ ovT) {
  __shared__ ushort As[4096], Bs[4096];
  int z = blockIdx.z;
  const ushort* A  = (z == 0) ? xq : (z == 1) ? xk : xv;
  const ushort* Bt = (z == 0) ? wq : (z == 1) ? wk : wv;
  const float* bias = (z == 0) ? bq : (z == 1) ? bk : bv;
  float s_inv = fmaxf(amax[z], 1e-12f) * (1.0f / E4M3_MAX);
  if (z == 2)
    gemm_body<2, 128>(A, Bt, bias, s_inv, ovT, nullptr, blockIdx.x, blockIdx.y, As, Bs);
  else
    gemm_body<1, 128>(A, Bt, bias, s_inv, (z == 0) ? oq : ok, nullptr,
                      blockIdx.x, blockIdx.y, As, Bs);
}

// Output projection: 128x64 tile -> grid (16, 32) = 512 blocks (2/CU).
__global__ __launch_bounds__(256) void gemm_wo(const ushort* __restrict__ A,
                                               const ushort* __restrict__ Bt,
                                               const float* __restrict__ bias,
                                               float* __restrict__ out) {
  __shared__ ushort As[4096], Bs[2048];
  gemm_body<0, 64>(A, Bt, bias, 1.0f, nullptr, out, blockIdx.x, blockIdx.y, As, Bs);
}

// In-place rotary on bf16 q/k (unchanged).
__global__ __launch_bounds__(256) void rotary_bf(ushort* qb, ushort* kb) {
  int bs = blockIdx.x;
  int s = bs & 2047;
  int tid = threadIdx.x;
  int e = tid & 63, w = tid >> 6;
  int j = e & 31;
  float inv_freq = exp2f((float)j * (-13.287712379549449f / 32.0f));
  float ang = (float)s * inv_freq;
  float c = cosf(ang), sn = sinf(ang);
  float sgn = (e < 32) ? -1.0f : 1.0f;
  size_t base = (size_t)bs * 1024;
  #pragma unroll
  for (int i = 0; i < 4; i++) {
    int h = w + i * 4;
    size_t idx = base + (size_t)h * 64 + e;
    float x = bf2f(qb[idx]);
    float xp = __shfl_xor(x, 32);
    qb[idx] = f2bf(x * c + sgn * xp * sn);
    float y = bf2f(kb[idx]);
    float yp = __shfl_xor(y, 32);
    kb[idx] = f2bf(y * c + sgn * yp * sn);
  }
}

// ---- Flash v5: paired q-tiles (perfect balance), P2 stride 68 (2-way banks). ----
// Grid (8,16,2): block pidx handles q-tiles {15-pidx, pidx} sequentially. 34 kv-iters each.
#define P2S 68   // P2 row stride in shorts: 136B = 2-bank rotation/row -> free 2-way
__global__ __launch_bounds__(256, 2) void flash_mfma5(const ushort* __restrict__ qb,
                                                      const ushort* __restrict__ kb,
                                                      const ushort* __restrict__ vT,
                                                      ushort* __restrict__ zb) {
  int pidx = blockIdx.x;
  int h = blockIdx.y, b = blockIdx.z;
  int tid = threadIdx.x;
  int w = tid >> 6, lane = tid & 63, h2 = lane >> 5, l31 = lane & 31;
  __shared__ ushort sbuf[8192 + 9216];   // Ks[4096] | Vs[4096] | P2 128xP2S (epi: Osb 128x72)
  ushort* Ks = sbuf;
  ushort* Vs = sbuf + 4096;
  ushort* P2 = sbuf + 8192;

  // staging geometry (fixed per thread): unit u -> (row r, 16B chunk c), XOR swizzle
  const int u0 = tid, u1 = tid + 256;
  const int r0 = u0 >> 3, c0 = u0 & 7, r1 = u1 >> 3, c1 = u1 & 7;
  const int sw0 = (c0 ^ (r0 & 7)) * 8, sw1 = (c1 ^ (r1 & 7)) * 8;
  const ushort* ksrc0 = kb + ((size_t)(b * 2048 + r0)) * 1024 + (size_t)h * 64 + c0 * 8;
  const ushort* ksrc1 = kb + ((size_t)(b * 2048 + r1)) * 1024 + (size_t)h * 64 + c1 * 8;
  const ushort* vsrc0 = vT + ((size_t)((b * 16 + h) * 64 + r0)) * 2048 + c0 * 8;
  const ushort* vsrc1 = vT + ((size_t)((b * 16 + h) * 64 + r1)) * 2048 + c1 * 8;

  const float CE = 0.125f;               // 1/sqrt(64)
  const int qrow = w * 32 + l31;         // block-local q row

  #pragma unroll 1
  for (int t = 0; t < 2; t++) {
    const int qt = (t == 0) ? (15 - pidx) : pidx;
    const int q0 = qt * 128;
    const int qg = q0 + qrow;            // this lane's q (column of S^T)
    size_t qbase = ((size_t)(b * 2048 + qg)) * 1024 + (size_t)h * 64;
    bf16x8 qf[4];                        // Q B-frags: slot (h2,j) of chunk ck <- e=16ck+8h2+j
    #pragma unroll
    for (int ck = 0; ck < 4; ck++)
      qf[ck] = *(const bf16x8*)&qb[qbase + ck * 16 + h2 * 8];

    f32x16 accO[2] = {};                 // O^T: rows e (2 frags), col q
    float mrun = -INFINITY, lrun = 0.0f;

    int ktmax = 2 * qt + 1;
    uint4 kc0 = *(const uint4*)ksrc0;    // prefetch tile 0
    uint4 kc1 = *(const uint4*)ksrc1;
    uint4 vc0 = *(const uint4*)vsrc0;
    uint4 vc1 = *(const uint4*)vsrc1;

    for (int kt = 0; kt <= ktmax; kt++) {
      __syncthreads();                   // prev iter's LDS reads done
      *(uint4*)&Ks[r0 * 64 + sw0] = kc0;
      *(uint4*)&Ks[r1 * 64 + sw1] = kc1;
      *(uint4*)&Vs[r0 * 64 + sw0] = vc0;
      *(uint4*)&Vs[r1 * 64 + sw1] = vc1;
      __syncthreads();
      if (kt < ktmax) {                  // prefetch kt+1; in flight across compute
        kc0 = *(const uint4*)(ksrc0 + (size_t)(kt + 1) * 65536);
        kc1 = *(const uint4*)(ksrc1 + (size_t)(kt + 1) * 65536);
        vc0 = *(const uint4*)(vsrc0 + (kt + 1) * 64);
        vc1 = *(const uint4*)(vsrc1 + (kt + 1) * 64);
      }

      bool active = (kt * 64 <= q0 + w * 32 + 31);  // wave-uniform
      if (active) {
        // S^T = K . Q^T   (M=kv 2 frags of 32, K=e in 4 chunks of 16)
        f32x16 sc[2] = {};
        #pragma unroll
        for (int mf = 0; mf < 2; mf++) {
          int row = mf * 32 + l31;
          int s8 = row & 7;
          #pragma unroll
          for (int ck = 0; ck < 4; ck++) {
            bf16x8 ka = *(const bf16x8*)&Ks[row * 64 + (((2 * ck + h2) ^ s8) * 8)];
            sc[mf] = __builtin_amdgcn_mfma_f32_32x32x16_bf16(ka, qf[ck], sc[mf], 0, 0, 0);
          }
        }

        // causal mask (raw domain: -8000 * 0.125 = -1000 matches ref IGNORE)
        if (kt * 64 + 63 > q0 + w * 32) {
          #pragma unroll
          for (int mf = 0; mf < 2; mf++)
            #pragma unroll
            for (int i = 0; i < 16; i++) {
              int kv = kt * 64 + mf * 32 + (i & 3) + 8 * (i >> 2) + 4 * h2;
              sc[mf][i] = (kv > qg) ? -8000.0f : sc[mf][i];
            }
        }

        // online softmax: in-register (32 values/lane) + one xor-32 shuffle
        float tm = sc[0][0];
        #pragma unroll
        for (int i = 1; i < 16; i++) tm = fmaxf(tm, sc[0][i]);
        #pragma unroll
        for (int i = 0; i < 16; i++) tm = fmaxf(tm, sc[1][i]);
        tm = fmaxf(tm, __shfl_xor(tm, 32));
        float mnew = fmaxf(mrun, tm);
        float alpha = __expf((mrun - mnew) * CE);
        float p[2][16];
        float rs = 0.0f;
        #pragma unroll
        for (int mf = 0; mf < 2; mf++)
          #pragma unroll
          for (int i = 0; i < 16; i++) {
            float pv = __expf((sc[mf][i] - mnew) * CE);
            p[mf][i] = pv;
            rs += pv;
          }
        rs += __shfl_xor(rs, 32);
        lrun = lrun * alpha + rs;
        mrun = mnew;
        #pragma unroll
        for (int mf = 0; mf < 2; mf++)
          #pragma unroll
          for (int i = 0; i < 16; i++) accO[mf][i] *= alpha;

        // write P^T -> LDS as P2[q][kv] (stride P2S)
        #pragma unroll
        for (int mf = 0; mf < 2; mf++)
          #pragma unroll
          for (int m = 0; m < 4; m++) {
            uint2 w2;
            w2.x = pack2bf(p[mf][4 * m + 0], p[mf][4 * m + 1]);
            w2.y = pack2bf(p[mf][4 * m + 2], p[mf][4 * m + 3]);
            *(uint2*)&P2[qrow * P2S + 32 * mf + 8 * m + 4 * h2] = w2;
          }
      }
      __syncthreads();                   // P2 visible
      if (active) {
        // O^T += V^T . P^T ; B-frag slot (h2,j) of chunk ck <- P2[qrow][16ck+8h2+j]
        #pragma unroll
        for (int ck = 0; ck < 4; ck++) {
          uint2 lo = *(const uint2*)&P2[qrow * P2S + ck * 16 + h2 * 8];
          uint2 hi = *(const uint2*)&P2[qrow * P2S + ck * 16 + h2 * 8 + 4];
          uint4 pb4 = {lo.x, lo.y, hi.x, hi.y};
          bf16x8 pB = *(bf16x8*)&pb4;
          #pragma unroll
          for (int mf = 0; mf < 2; mf++) {
            int row = mf * 32 + l31;
            bf16x8 va = *(const bf16x8*)&Vs[row * 64 + (((2 * ck + h2) ^ (row & 7)) * 8)];
            accO[mf] = __builtin_amdgcn_mfma_f32_32x32x16_bf16(va, pB, accO[mf], 0, 0, 0);
          }
        }
      }
    }

    // epilogue: divide by l, transpose O^T->O through LDS (stride 72), coalesced store
    float inv = 1.0f / lrun;
    __syncthreads();                     // all waves done with P2/Ks/Vs
    ushort* Osb = P2;                    // 128 x 72
    #pragma unroll
    for (int mf = 0; mf < 2; mf++)
      #pragma unroll
      for (int m = 0; m < 4; m++) {
        int e0 = 32 * mf + 8 * m + 4 * h2;
        float a0 = accO[mf][4 * m + 0] * inv, a1 = accO[mf][4 * m + 1] * inv;
        float a2 = accO[mf][4 * m + 2] * inv, a3 = accO[mf][4 * m + 3] * inv;
        *(unsigned*)&Osb[qrow * 72 + e0] = pack2bf(a0, a1);
        *(unsigned*)&Osb[qrow * 72 + e0 + 2] = pack2bf(a2, a3);
      }
    __syncthreads();
    size_t obase = ((size_t)(b * 2048 + q0)) * 1024 + (size_t)h * 64;
    #pragma unroll
    for (int i = 0; i < 4; i++) {
      int u = tid + i * 256;             // 1024 units: 128 rows x 8 blocks
      int r = u >> 3, blk = u & 7;
      *(uint4*)&zb[obase + (size_t)r * 1024 + blk * 8] = *(const uint4*)&Osb[r * 72 + blk * 8];
    }
    // loop to next q-tile: first __syncthreads of next kv loop guards Osb reuse
  }
}

extern "C" void kernel_launch(void* const* d_in, const int* in_sizes, int n_in,
                              void* d_out, int out_size, void* d_ws, size_t ws_size,
                              hipStream_t stream) {
  const float* Xq  = (const float*)d_in[0];
  const float* Xk  = (const float*)d_in[1];
  const float* Xv  = (const float*)d_in[2];
  const float* W_Q = (const float*)d_in[3];
  const float* W_K = (const float*)d_in[4];
  const float* W_V = (const float*)d_in[5];
  const float* W_O = (const float*)d_in[6];
  const float* b_Q = (const float*)d_in[7];
  const float* b_K = (const float*)d_in[8];
  const float* b_V = (const float*)d_in[9];
  const float* b_O = (const float*)d_in[10];
  float* out = (float*)d_out;

  char* base = (char*)d_ws;
  float*  amax = (float*)(base + 0);
  float*  bq   = (float*)(base + 4096);
  float*  bk   = (float*)(base + 8192);
  float*  bv   = (float*)(base + 12288);
  ushort* wq   = (ushort*)(base + 16384);
  ushort* wk   = (ushort*)(base + 16384 + 2097152);
  ushort* wv   = (ushort*)(base + 16384 + 2u * 2097152);
  ushort* woT  = (ushort*)(base + 16384 + 3u * 2097152);
  ushort* xq   = (ushort*)(base + 8404992);
  ushort* xk   = (ushort*)(base + 16793600);
  ushort* xv   = (ushort*)(base + 25182208);
  ushort* qbf  = (ushort*)(base + 33570816);
  ushort* kbf  = (ushort*)(base + 41959424);
  ushort* vT   = (ushort*)(base + 50348032);  // written directly by gemm3 z=2
  ushort* zbf  = xk;   // xk dead after gemm3_qkv

  zero16_kernel<<<1, 64, 0, stream>>>(amax);
  dim3 agrid(256, 6);
  amax6_kernel<<<agrid, 256, 0, stream>>>(W_Q, W_K, W_V, b_Q, b_K, b_V, amax);

  dim3 rgrid(16, 16, 3);
  quant_repack_bt3<<<rgrid, 256, 0, stream>>>(W_Q, W_K, W_V, amax, wq, wk, wv);
  dim3 qvgrid(4, 3);
  qvec3_kernel<<<qvgrid, 256, 0, stream>>>(b_Q, b_K, b_V, amax, bq, bk, bv);
  dim3 wgrid(16, 16);
  wo_trans<<<wgrid, 256, 0, stream>>>(W_O, woT);
  dim3 cgrid(4096, 3);
  cvt3_kernel<<<cgrid, 256, 0, stream>>>(Xq, Xk, Xv, xq, xk, xv);

  dim3 g3(8, 32, 3);   // batched QKV: 768 blocks ~3/CU; z=2 emits V^T
  gemm3_qkv<<<g3, 256, 0, stream>>>(xq, xk, xv, wq, wk, wv, bq, bk, bv, amax,
                                    qbf, kbf, vT);

  rotary_bf<<<4096, 256, 0, stream>>>(qbf, kbf);

  dim3 fgrid(8, 16, 2);   // paired q-tiles: 256 perfectly-balanced blocks
  flash_mfma5<<<fgrid, 256, 0, stream>>>(qbf, kbf, vT, zbf);

  dim3 wog(16, 32);    // 128x64 tiles: 512 blocks (2/CU)
  gemm_wo<<<wog, 256, 0, stream>>>(zbf, woT, b_O, out);
}